// Round 6
// baseline (541.432 us; speedup 1.0000x reference)
//
#include <hip/hip_runtime.h>
#include <math.h>

#define B_ 64
#define T_ 2048
#define DL 1024
#define DE 512
#define DA 128
#define NF 32
#define KW 31
#define PADW 15
#define TT 128
#define LDA 40   // bf16 LDS row stride: 32 cols + 8 pad

typedef short bf16x8 __attribute__((ext_vector_type(8)));
typedef float f32x4 __attribute__((ext_vector_type(4)));

// split fp32 into bf16 hi + bf16 lo (RNE), x ~= hi + lo to ~2^-17 rel
__device__ __forceinline__ void split_bf16(float x, unsigned short &hi, unsigned short &lo) {
    unsigned u = __float_as_uint(x);
    unsigned short h = (unsigned short)((u + 0x7FFFu + ((u >> 16) & 1u)) >> 16);
    float hf = __uint_as_float((unsigned)h << 16);
    float l = x - hf;
    unsigned ul = __float_as_uint(l);
    hi = h;
    lo = (unsigned short)((ul + 0x7FFFu + ((ul >> 16) & 1u)) >> 16);
}

__device__ __forceinline__ float fast_tanh(float x) {
    x = fminf(fmaxf(x, -15.f), 15.f);
    float e2 = __expf(2.f * x);
    return (e2 - 1.f) * __builtin_amdgcn_rcpf(e2 + 1.f);
}

// ---------------- prep: split Wm [128][512] and Wloc [128][32] into bf16 hi/lo ----------------
__global__ __launch_bounds__(256) void prep_kernel(const float* __restrict__ Wm,
                                                   const float* __restrict__ Wloc,
                                                   unsigned short* __restrict__ bg_hi,
                                                   unsigned short* __restrict__ bg_lo,
                                                   unsigned short* __restrict__ bw_hi,
                                                   unsigned short* __restrict__ bw_lo) {
    int i = blockIdx.x * 256 + threadIdx.x;  // 65536 + 4096 elements
    unsigned short h, l;
    if (i < DA * DE) {
        split_bf16(Wm[i], h, l);
        bg_hi[i] = h;
        bg_lo[i] = l;
    } else {
        int j = i - DA * DE;
        split_bf16(Wloc[j], h, l);
        bw_hi[j] = h;
        bw_lo[j] = l;
    }
}

// ---------------- q = query @ Wq.T + bq  ([B,128]) ----------------
__global__ __launch_bounds__(128) void q_kernel(const float* __restrict__ query,
                                                const float* __restrict__ Wq,
                                                const float* __restrict__ bq,
                                                float* __restrict__ qbuf) {
    int b = blockIdx.x;
    int a = threadIdx.x;
    __shared__ __align__(16) float qs[DL];
    for (int i = threadIdx.x; i < DL; i += 128) qs[i] = query[(size_t)b * DL + i];
    __syncthreads();
    const float* wrow = Wq + (size_t)a * DL;
    float acc = 0.f;
#pragma unroll 8
    for (int i = 0; i < DL; i += 4) {
        float4 w = *(const float4*)(wrow + i);
        float4 q4 = *(const float4*)(qs + i);
        acc += w.x * q4.x + w.y * q4.y + w.z * q4.z + w.w * q4.w;
    }
    qbuf[(size_t)b * DA + a] = acc + bq[a];
}

// ---------------- energies via split-bf16 MFMA + fused local-softmax PV ----------------
// Round-5 GEMM core (MFMA pass reorder + T14 issue-early A prefetch), plus:
//  - flash-style fused PV: block computes local max/exp-sum over its 128 energies
//    and an unnormalized partial context from its (L2/L3-hot) memory tile.
//    Eliminates the separate 256-MB ctx_partial pass.
//  - __launch_bounds__(256,3): LDS 52.7 KB fits 3 blocks/CU (was 2).
__global__ __launch_bounds__(256, 3) void energy_kernel(
    const float* __restrict__ mem,            // [B,T,512]
    const float* __restrict__ attw,           // [B,2,T]
    const unsigned short* __restrict__ bg_hi, // Wm hi bf16 [128][512]
    const unsigned short* __restrict__ bg_lo, // Wm lo bf16 [128][512]
    const unsigned short* __restrict__ bw_hi, // Wloc hi bf16 [128][32]
    const unsigned short* __restrict__ bw_lo, // Wloc lo bf16 [128][32]
    const float* __restrict__ bm,
    const float* __restrict__ Wconv,          // [32,2,31]
    const float* __restrict__ Wv,
    const float* __restrict__ bv,
    const float* __restrict__ qbuf,           // [B,128]
    float* __restrict__ e_out,                // [B,T]
    float* __restrict__ pctx,                 // [B,16,512] unnormalized partial ctx
    float* __restrict__ msbuf)                // [B,16,2] local (max, expsum)
{
    __shared__ __align__(16) unsigned short Ahi[TT * LDA];
    __shared__ __align__(16) unsigned short Alo[TT * LDA];
    __shared__ __align__(16) unsigned short Bhi[DA * LDA];
    __shared__ __align__(16) unsigned short Blo[DA * LDA];
    __shared__ __align__(16) float attw_s[2 * 160];   // reused: PV reductions
    __shared__ __align__(16) float wconv_s[NF * 64];  // reused: PV p_s[128]
    __shared__ float qb_s[DA], wv_s[DA];
    __shared__ float e_part[2][TT];

    const int tid = threadIdx.x;
    const int b = blockIdx.y;
    const int tc = blockIdx.x;
    const int t0 = tc * TT;
    const int lane = tid & 63;
    const int wave = tid >> 6;
    const int wm = wave & 1, wn = wave >> 1;
    const int m = lane & 15;
    const int q8 = (lane >> 4) * 8;

    if (tid < DA) {
        qb_s[tid] = qbuf[(size_t)b * DA + tid] + bm[tid];
        wv_s[tid] = Wv[tid];
    }

    // stage attw slice + wconv
    for (int i = tid; i < 2 * (TT + KW - 1); i += 256) {
        int c = i / 158, j = i % 158;
        int t = t0 - PADW + j;
        attw_s[c * 160 + j] = (t >= 0 && t < T_) ? attw[((size_t)b * 2 + c) * T_ + t] : 0.f;
    }
    for (int i = tid; i < NF * 2 * KW; i += 256) {
        int f = i / 62, r = i % 62;
        wconv_s[f * 64 + r] = Wconv[i];
    }
    __syncthreads();

    // conv chunk: A <- conv[t][f] split; B <- pre-split Wloc copy (cols 0..31)
    for (int i = tid; i < TT * NF; i += 256) {
        int t = i >> 5, f = i & 31;
        const float* w0 = wconv_s + f * 64;
        const float* a0 = attw_s + t;
        const float* a1 = attw_s + 160 + t;
        float s = 0.f;
#pragma unroll
        for (int k = 0; k < KW; ++k) s += w0[k] * a0[k] + w0[31 + k] * a1[k];
        unsigned short h, l;
        split_bf16(s, h, l);
        Ahi[t * LDA + f] = h;
        Alo[t * LDA + f] = l;
    }
#pragma unroll
    for (int r = 0; r < 2; ++r) {
        int idx = tid + 256 * r;
        int a = idx >> 2, c8 = (idx & 3) * 8;
        *(uint4*)(Bhi + a * LDA + c8) = *(const uint4*)(bw_hi + a * NF + c8);
        *(uint4*)(Blo + a * LDA + c8) = *(const uint4*)(bw_lo + a * NF + c8);
    }
    __syncthreads();

    f32x4 acc[4][4];
#pragma unroll
    for (int mi = 0; mi < 4; ++mi)
#pragma unroll
        for (int ni = 0; ni < 4; ++ni) {
            f32x4 z = {0.f, 0.f, 0.f, 0.f};
            acc[mi][ni] = z;
        }

    // MFMA step: fragments up-front, 3 passes of 16 independent MFMAs.
    auto mfma_step = [&]() {
        bf16x8 ah[4], al[4], bh[4], bl[4];
#pragma unroll
        for (int mi = 0; mi < 4; ++mi) {
            int r = (wm * 64 + mi * 16 + m) * LDA + q8;
            ah[mi] = *(const bf16x8*)(Ahi + r);
            al[mi] = *(const bf16x8*)(Alo + r);
        }
#pragma unroll
        for (int ni = 0; ni < 4; ++ni) {
            int r = (wn * 64 + ni * 16 + m) * LDA + q8;
            bh[ni] = *(const bf16x8*)(Bhi + r);
            bl[ni] = *(const bf16x8*)(Blo + r);
        }
        __builtin_amdgcn_s_setprio(1);
#pragma unroll
        for (int ni = 0; ni < 4; ++ni)
#pragma unroll
            for (int mi = 0; mi < 4; ++mi)
                acc[mi][ni] = __builtin_amdgcn_mfma_f32_16x16x32_bf16(ah[mi], bh[ni], acc[mi][ni], 0, 0, 0);
#pragma unroll
        for (int ni = 0; ni < 4; ++ni)
#pragma unroll
            for (int mi = 0; mi < 4; ++mi)
                acc[mi][ni] = __builtin_amdgcn_mfma_f32_16x16x32_bf16(ah[mi], bl[ni], acc[mi][ni], 0, 0, 0);
#pragma unroll
        for (int ni = 0; ni < 4; ++ni)
#pragma unroll
            for (int mi = 0; mi < 4; ++mi)
                acc[mi][ni] = __builtin_amdgcn_mfma_f32_16x16x32_bf16(al[mi], bh[ni], acc[mi][ni], 0, 0, 0);
        __builtin_amdgcn_s_setprio(0);
    };

    const size_t mem_base = ((size_t)b * T_ + t0) * DE;

    // T14 prologue: issue chunk-0 A loads (in flight across conv mfma_step)
    float4 rA[4];
#pragma unroll
    for (int r = 0; r < 4; ++r) {
        int idx = tid + 256 * r;
        int t = idx >> 3, c4 = (idx & 7) * 4;
        rA[r] = *(const float4*)(mem + mem_base + (size_t)t * DE + c4);
    }

    mfma_step();  // conv/location chunk

#pragma unroll 1
    for (int c = 0; c < 16; ++c) {
        const int k0 = c * 32;
        asm volatile("s_barrier" ::: "memory");  // no vmcnt drain
        uint4 rbh[2], rbl[2];
#pragma unroll
        for (int r = 0; r < 2; ++r) {
            int idx = tid + 256 * r;
            int a = idx >> 2, c8 = (idx & 3) * 8;
            rbh[r] = *(const uint4*)(bg_hi + (size_t)a * DE + k0 + c8);
            rbl[r] = *(const uint4*)(bg_lo + (size_t)a * DE + k0 + c8);
        }
#pragma unroll
        for (int r = 0; r < 4; ++r) {
            int idx = tid + 256 * r;
            int t = idx >> 3, c4 = (idx & 7) * 4;
            unsigned short h0, l0, h1, l1, h2, l2, h3, l3;
            split_bf16(rA[r].x, h0, l0);
            split_bf16(rA[r].y, h1, l1);
            split_bf16(rA[r].z, h2, l2);
            split_bf16(rA[r].w, h3, l3);
            ushort4 hv = {h0, h1, h2, h3};
            ushort4 lv = {l0, l1, l2, l3};
            *(ushort4*)(Ahi + t * LDA + c4) = hv;
            *(ushort4*)(Alo + t * LDA + c4) = lv;
        }
#pragma unroll
        for (int r = 0; r < 2; ++r) {
            int idx = tid + 256 * r;
            int a = idx >> 2, c8 = (idx & 3) * 8;
            *(uint4*)(Bhi + a * LDA + c8) = rbh[r];
            *(uint4*)(Blo + a * LDA + c8) = rbl[r];
        }
        if (c < 15) {
            const int k0n = k0 + 32;
#pragma unroll
            for (int r = 0; r < 4; ++r) {
                int idx = tid + 256 * r;
                int t = idx >> 3, c4 = (idx & 7) * 4;
                rA[r] = *(const float4*)(mem + mem_base + (size_t)t * DE + k0n + c4);
            }
        }
        asm volatile("s_waitcnt lgkmcnt(0)\n\ts_barrier" ::: "memory");
        mfma_step();
    }

    // epilogue: e[t] = bv + sum_a wv[a]*tanh(acc + qb[a])
    float wvr[4], qbr[4];
#pragma unroll
    for (int ni = 0; ni < 4; ++ni) {
        int a = wn * 64 + ni * 16 + m;
        wvr[ni] = wv_s[a];
        qbr[ni] = qb_s[a];
    }
    float bvv = bv[0];
#pragma unroll
    for (int mi = 0; mi < 4; ++mi) {
#pragma unroll
        for (int reg = 0; reg < 4; ++reg) {
            float s = 0.f;
#pragma unroll
            for (int ni = 0; ni < 4; ++ni)
                s += wvr[ni] * fast_tanh(acc[mi][ni][reg] + qbr[ni]);
            s += __shfl_xor(s, 1, 64);
            s += __shfl_xor(s, 2, 64);
            s += __shfl_xor(s, 4, 64);
            s += __shfl_xor(s, 8, 64);
            if (m == 0)
                e_part[wn][wm * 64 + mi * 16 + (lane >> 4) * 4 + reg] = s;
        }
    }
    __syncthreads();

    // ---- fused PV: local softmax over this block's 128 energies + partial ctx ----
    float ee = -1e30f;
    if (tid < TT) {
        ee = e_part[0][tid] + e_part[1][tid] + bvv;
        e_out[(size_t)b * T_ + t0 + tid] = ee;
    }
    float* redf = attw_s;   // dead since conv phase
    float* p_s = wconv_s;   // dead since conv phase
    float mx = ee;
#pragma unroll
    for (int off = 32; off >= 1; off >>= 1) mx = fmaxf(mx, __shfl_xor(mx, off, 64));
    if (lane == 0) redf[wave] = mx;
    __syncthreads();
    const float m_loc = fmaxf(fmaxf(redf[0], redf[1]), fmaxf(redf[2], redf[3]));
    float pt = 0.f;
    if (tid < TT) {
        pt = __expf(ee - m_loc);
        p_s[tid] = pt;
    }
    float ss = pt;
#pragma unroll
    for (int off = 32; off >= 1; off >>= 1) ss += __shfl_xor(ss, off, 64);
    if (lane == 0) redf[8 + wave] = ss;
    __syncthreads();
    if (tid == 0) {
        const float s_loc = redf[8] + redf[9] + redf[10] + redf[11];
        msbuf[((size_t)b * 16 + tc) * 2 + 0] = m_loc;
        msbuf[((size_t)b * 16 + tc) * 2 + 1] = s_loc;
    }
    // partial context: ctx_d = sum_t p_t * mem[t][d]; 256 threads x 2 d
    const int d0 = tid * 2;
    const float* mp = mem + mem_base + d0;
    float c0 = 0.f, c1 = 0.f;
#pragma unroll 8
    for (int t = 0; t < TT; ++t) {
        float pv = p_s[t];
        float2 v = *(const float2*)(mp + (size_t)t * DE);
        c0 += pv * v.x;
        c1 += pv * v.y;
    }
    float2 cv = {c0, c1};
    *(float2*)(pctx + ((size_t)b * 16 + tc) * DE + d0) = cv;
}

// ---------------- softmax over T per b (w_out) + combine partial ctx ----------------
__global__ __launch_bounds__(256) void softmax_ctx_kernel(const float* __restrict__ e,
                                                          const float* __restrict__ msbuf,
                                                          const float* __restrict__ pctx,
                                                          float* __restrict__ wout,
                                                          float* __restrict__ ctx) {
    int b = blockIdx.x;
    int tid = threadIdx.x;
    __shared__ float red[4];
    __shared__ float scl[16];
    float v[8];
    float m = -1e30f;
#pragma unroll
    for (int r = 0; r < 8; ++r) {
        v[r] = e[(size_t)b * T_ + r * 256 + tid];
        m = fmaxf(m, v[r]);
    }
#pragma unroll
    for (int off = 1; off < 64; off <<= 1) m = fmaxf(m, __shfl_xor(m, off, 64));
    if ((tid & 63) == 0) red[tid >> 6] = m;
    __syncthreads();
    m = fmaxf(fmaxf(red[0], red[1]), fmaxf(red[2], red[3]));
    __syncthreads();
    float s = 0.f;
#pragma unroll
    for (int r = 0; r < 8; ++r) {
        v[r] = expf(v[r] - m);
        s += v[r];
    }
#pragma unroll
    for (int off = 1; off < 64; off <<= 1) s += __shfl_xor(s, off, 64);
    if ((tid & 63) == 0) red[tid >> 6] = s;
    __syncthreads();
    s = red[0] + red[1] + red[2] + red[3];
    float inv = 1.0f / s;
#pragma unroll
    for (int r = 0; r < 8; ++r) wout[(size_t)b * T_ + r * 256 + tid] = v[r] * inv;

    // ---- combine partial contexts ----
    float mj = (tid < 16) ? msbuf[((size_t)b * 16 + tid) * 2 + 0] : -1e30f;
    float sj = (tid < 16) ? msbuf[((size_t)b * 16 + tid) * 2 + 1] : 0.f;
    float M = mj;
#pragma unroll
    for (int off = 8; off >= 1; off >>= 1) M = fmaxf(M, __shfl_xor(M, off, 64));
    float sc = sj * __expf(mj - M);
    float S = sc;
#pragma unroll
    for (int off = 8; off >= 1; off >>= 1) S += __shfl_xor(S, off, 64);
    if (tid < 16) scl[tid] = __expf(mj - M) / S;
    __syncthreads();
    const int d0 = tid * 2;
    float c0 = 0.f, c1 = 0.f;
#pragma unroll
    for (int j = 0; j < 16; ++j) {
        float sv = scl[j];
        float2 pv = *(const float2*)(pctx + ((size_t)b * 16 + j) * DE + d0);
        c0 += sv * pv.x;
        c1 += sv * pv.y;
    }
    float2 cv = {c0, c1};
    *(float2*)(ctx + (size_t)b * DE + d0) = cv;
}

extern "C" void kernel_launch(void* const* d_in, const int* in_sizes, int n_in,
                              void* d_out, int out_size, void* d_ws, size_t ws_size,
                              hipStream_t stream) {
    const float* query  = (const float*)d_in[0];
    const float* memory = (const float*)d_in[1];
    const float* attw   = (const float*)d_in[2];
    const float* Wq     = (const float*)d_in[3];
    const float* bq     = (const float*)d_in[4];
    const float* Wm     = (const float*)d_in[5];
    const float* bm     = (const float*)d_in[6];
    const float* Wconv  = (const float*)d_in[7];
    const float* Wloc   = (const float*)d_in[8];
    const float* Wv     = (const float*)d_in[9];
    const float* bv     = (const float*)d_in[10];

    float* out = (float*)d_out;
    float* ctx_out = out;          // [64,512]
    float* w_out = out + B_ * DE;  // [64,2048]

    float* ws = (float*)d_ws;
    float* qbuf = ws;                          // 8192 f
    float* ebuf = qbuf + B_ * DA;              // 131072 f
    float* pctx = ebuf + (size_t)B_ * T_;      // 524288 f
    float* msbuf = pctx + (size_t)B_ * 16 * DE;  // 2048 f
    unsigned short* bg_hi = (unsigned short*)(msbuf + B_ * 16 * 2);
    unsigned short* bg_lo = bg_hi + DA * DE;
    unsigned short* bw_hi = bg_lo + DA * DE;
    unsigned short* bw_lo = bw_hi + DA * NF;

    prep_kernel<<<dim3((DA * DE + DA * NF) / 256), dim3(256), 0, stream>>>(
        Wm, Wloc, bg_hi, bg_lo, bw_hi, bw_lo);
    q_kernel<<<dim3(B_), dim3(128), 0, stream>>>(query, Wq, bq, qbuf);
    energy_kernel<<<dim3(T_ / TT, B_), dim3(256), 0, stream>>>(
        memory, attw, bg_hi, bg_lo, bw_hi, bw_lo, bm, Wconv, Wv, bv, qbuf,
        ebuf, pctx, msbuf);
    softmax_ctx_kernel<<<dim3(B_), dim3(256), 0, stream>>>(ebuf, msbuf, pctx, w_out, ctx_out);
}